// Round 1
// baseline (188.453 us; speedup 1.0000x reference)
//
#include <hip/hip_runtime.h>
#include <math.h>

#define N_PTS 131072
#define BPB   64                 // blocks per batch (reduction chunks)
#define CHUNK (N_PTS / BPB)      // 2048 elements per block
#define TPB   256
#define NACC  16                 // W, As[3], At[3], M[9]

// ---------------- Kernel 1: streaming partial reduction ----------------
__global__ __launch_bounds__(TPB) void ego_partial_kernel(
    const float* __restrict__ xyz_s,    // (B,3,N)
    const float* __restrict__ wtgt,     // (B,3,N)
    const float* __restrict__ weights,  // (B,1,N)
    const float* __restrict__ label,    // (B,1,N)
    float* __restrict__ partials)       // (B, BPB, 16)
{
    const int b     = blockIdx.y;
    const int chunk = blockIdx.x;
    const int t     = threadIdx.x;

    const size_t baseN  = (size_t)b * N_PTS + (size_t)chunk * CHUNK;
    const size_t base3  = (size_t)b * 3 * N_PTS + (size_t)chunk * CHUNK;

    const float4* w4  = (const float4*)(weights + baseN);
    const float4* l4  = (const float4*)(label   + baseN);
    const float4* xs0 = (const float4*)(xyz_s + base3);
    const float4* xs1 = (const float4*)(xyz_s + base3 + N_PTS);
    const float4* xs2 = (const float4*)(xyz_s + base3 + 2 * N_PTS);
    const float4* xt0 = (const float4*)(wtgt  + base3);
    const float4* xt1 = (const float4*)(wtgt  + base3 + N_PTS);
    const float4* xt2 = (const float4*)(wtgt  + base3 + 2 * N_PTS);

    float acc[NACC];
#pragma unroll
    for (int i = 0; i < NACC; ++i) acc[i] = 0.0f;

#pragma unroll
    for (int k = 0; k < CHUNK / 4 / TPB; ++k) {   // 2 iterations
        const int i = t + k * TPB;
        const float4 wv = w4[i];
        const float4 lv = l4[i];
        const float4 a0 = xs0[i], a1 = xs1[i], a2 = xs2[i];
        const float4 b0 = xt0[i], b1 = xt1[i], b2 = xt2[i];

#define ACCUM(C)                                              \
        {                                                     \
            const float w  = wv.C * fabsf(lv.C - 1.0f);       \
            const float s0 = a0.C, s1 = a1.C, s2 = a2.C;      \
            const float t0 = b0.C, t1 = b1.C, t2 = b2.C;      \
            acc[0] += w;                                      \
            const float ws0 = w * s0, ws1 = w * s1, ws2 = w * s2; \
            acc[1] += ws0;  acc[2] += ws1;  acc[3] += ws2;    \
            acc[4] += w * t0; acc[5] += w * t1; acc[6] += w * t2; \
            acc[7]  += ws0 * t0; acc[8]  += ws0 * t1; acc[9]  += ws0 * t2; \
            acc[10] += ws1 * t0; acc[11] += ws1 * t1; acc[12] += ws1 * t2; \
            acc[13] += ws2 * t0; acc[14] += ws2 * t1; acc[15] += ws2 * t2; \
        }
        ACCUM(x) ACCUM(y) ACCUM(z) ACCUM(w)
#undef ACCUM
    }

    // wave-level reduce (64 lanes)
#pragma unroll
    for (int i = 0; i < NACC; ++i) {
        float v = acc[i];
#pragma unroll
        for (int off = 32; off > 0; off >>= 1)
            v += __shfl_down(v, off, 64);
        acc[i] = v;
    }

    __shared__ float red[TPB / 64][NACC];
    const int wave = t >> 6;
    const int lane = t & 63;
    if (lane == 0) {
#pragma unroll
        for (int i = 0; i < NACC; ++i) red[wave][i] = acc[i];
    }
    __syncthreads();

    if (t < NACC) {
        float v = 0.0f;
#pragma unroll
        for (int wv_ = 0; wv_ < TPB / 64; ++wv_) v += red[wv_][t];
        partials[((size_t)b * BPB + chunk) * NACC + t] = v;
    }
}

// ---------------- Kernel 2: final reduce + 3x3 SVD Kabsch ----------------
__global__ __launch_bounds__(64) void ego_finalize_kernel(
    const float* __restrict__ partials,  // (B, BPB, 16)
    float* __restrict__ out,             // rot (B,3,3) then translation (B,3,1)
    int B)
{
    const int b = blockIdx.x;
    const int t = threadIdx.x;   // 0..63 == BPB

    double acc[NACC];
    const float* p = partials + ((size_t)b * BPB + t) * NACC;
#pragma unroll
    for (int i = 0; i < NACC; ++i) acc[i] = (double)p[i];

#pragma unroll
    for (int i = 0; i < NACC; ++i) {
        double v = acc[i];
#pragma unroll
        for (int off = 32; off > 0; off >>= 1)
            v += __shfl_down(v, off, 64);
        acc[i] = v;
    }

    if (t != 0) return;

    const double W     = acc[0];
    const double denom = W + 1e-6;
    double cs[3], ct[3];
#pragma unroll
    for (int d = 0; d < 3; ++d) {
        cs[d] = acc[1 + d] / denom;
        ct[d] = acc[4 + d] / denom;
    }
    const double Wn = W / denom;

    double cov[3][3];
#pragma unroll
    for (int d = 0; d < 3; ++d)
#pragma unroll
        for (int e = 0; e < 3; ++e)
            cov[d][e] = acc[7 + d * 3 + e] / denom - cs[d] * ct[e] * (2.0 - Wn);

    // --- B = cov^T cov, Jacobi eigen-decomposition -> V, lambda ---
    double Bm[3][3];
    for (int i = 0; i < 3; ++i)
        for (int j = 0; j < 3; ++j) {
            double s = 0.0;
            for (int k = 0; k < 3; ++k) s += cov[k][i] * cov[k][j];
            Bm[i][j] = s;
        }
    double V[3][3] = {{1,0,0},{0,1,0},{0,0,1}};

    for (int sweep = 0; sweep < 30; ++sweep) {
        const double off = fabs(Bm[0][1]) + fabs(Bm[0][2]) + fabs(Bm[1][2]);
        if (off < 1e-300) break;
        const int pq[3][2] = {{0,1},{0,2},{1,2}};
        for (int r = 0; r < 3; ++r) {
            const int pp = pq[r][0], qq = pq[r][1];
            const double apq = Bm[pp][qq];
            if (fabs(apq) < 1e-300) continue;
            const double tau = (Bm[qq][qq] - Bm[pp][pp]) / (2.0 * apq);
            const double tt  = (tau >= 0.0 ? 1.0 : -1.0) /
                               (fabs(tau) + sqrt(1.0 + tau * tau));
            const double c = 1.0 / sqrt(1.0 + tt * tt);
            const double s = tt * c;
            for (int k = 0; k < 3; ++k) {
                const double bkp = Bm[k][pp], bkq = Bm[k][qq];
                Bm[k][pp] = c * bkp - s * bkq;
                Bm[k][qq] = s * bkp + c * bkq;
            }
            for (int k = 0; k < 3; ++k) {
                const double bpk = Bm[pp][k], bqk = Bm[qq][k];
                Bm[pp][k] = c * bpk - s * bqk;
                Bm[qq][k] = s * bpk + c * bqk;
            }
            for (int k = 0; k < 3; ++k) {
                const double vkp = V[k][pp], vkq = V[k][qq];
                V[k][pp] = c * vkp - s * vkq;
                V[k][qq] = s * vkp + c * vkq;
            }
        }
    }

    // sort eigenvalues descending, permute V columns
    double lam[3] = {Bm[0][0], Bm[1][1], Bm[2][2]};
    int idx[3] = {0, 1, 2};
    for (int i = 0; i < 2; ++i)
        for (int j = i + 1; j < 3; ++j)
            if (lam[idx[j]] > lam[idx[i]]) { int tmp = idx[i]; idx[i] = idx[j]; idx[j] = tmp; }
    double Vs[3][3], sig[3];
    for (int c = 0; c < 3; ++c) {
        sig[c] = sqrt(fmax(lam[idx[c]], 0.0));
        for (int rr = 0; rr < 3; ++rr) Vs[rr][c] = V[rr][idx[c]];
    }

    // U columns: u_c = cov * v_c / sigma_c (normalize; cross-product fallback)
    double U[3][3];
    for (int c = 0; c < 3; ++c) {
        double u0 = 0, u1 = 0, u2 = 0;
        for (int k = 0; k < 3; ++k) {
            u0 += cov[0][k] * Vs[k][c];
            u1 += cov[1][k] * Vs[k][c];
            u2 += cov[2][k] * Vs[k][c];
        }
        const double nn = sqrt(u0 * u0 + u1 * u1 + u2 * u2);
        if (nn > 1e-150) {
            U[0][c] = u0 / nn; U[1][c] = u1 / nn; U[2][c] = u2 / nn;
        } else if (c == 2) {
            // cross of first two columns
            U[0][2] = U[1][0] * U[2][1] - U[2][0] * U[1][1];
            U[1][2] = U[2][0] * U[0][1] - U[0][0] * U[2][1];
            U[2][2] = U[0][0] * U[1][1] - U[1][0] * U[0][1];
        } else {
            U[0][c] = (c == 0); U[1][c] = (c == 1); U[2][c] = 0.0;
        }
    }

    // rot_pos = Vs * U^T
    double rot[3][3];
    for (int d = 0; d < 3; ++d)
        for (int e = 0; e < 3; ++e)
            rot[d][e] = Vs[d][0] * U[e][0] + Vs[d][1] * U[e][1] + Vs[d][2] * U[e][2];

    const double det =
        rot[0][0] * (rot[1][1] * rot[2][2] - rot[1][2] * rot[2][1]) -
        rot[0][1] * (rot[1][0] * rot[2][2] - rot[1][2] * rot[2][0]) +
        rot[0][2] * (rot[1][0] * rot[2][1] - rot[1][1] * rot[2][0]);

    if (!(det > 0.0)) {
        // flip last column of V: rot = Vs * diag(1,1,-1) * U^T
        for (int d = 0; d < 3; ++d)
            for (int e = 0; e < 3; ++e)
                rot[d][e] = Vs[d][0] * U[e][0] + Vs[d][1] * U[e][1] - Vs[d][2] * U[e][2];
    }

    double tr[3];
    for (int d = 0; d < 3; ++d)
        tr[d] = -(rot[d][0] * cs[0] + rot[d][1] * cs[1] + rot[d][2] * cs[2]) + ct[d];

    // outputs: rot (B,3,3) flat, then translation (B,3,1) flat
    for (int d = 0; d < 3; ++d)
        for (int e = 0; e < 3; ++e)
            out[(size_t)b * 9 + d * 3 + e] = (float)rot[d][e];
    for (int d = 0; d < 3; ++d)
        out[(size_t)B * 9 + (size_t)b * 3 + d] = (float)tr[d];
}

extern "C" void kernel_launch(void* const* d_in, const int* in_sizes, int n_in,
                              void* d_out, int out_size, void* d_ws, size_t ws_size,
                              hipStream_t stream) {
    const float* xyz_s   = (const float*)d_in[0];
    const float* wtgt    = (const float*)d_in[1];
    const float* weights = (const float*)d_in[2];
    const float* label   = (const float*)d_in[3];
    float* out = (float*)d_out;
    float* partials = (float*)d_ws;   // B*BPB*16 floats = 128 KB

    const int B = in_sizes[2] / N_PTS;   // weights has B*N elements

    dim3 grid1(BPB, B);
    ego_partial_kernel<<<grid1, TPB, 0, stream>>>(xyz_s, wtgt, weights, label, partials);
    ego_finalize_kernel<<<B, 64, 0, stream>>>(partials, out, B);
}

// Round 2
// 163.316 us; speedup vs baseline: 1.1539x; 1.1539x over previous
//
#include <hip/hip_runtime.h>
#include <math.h>

#define N_PTS 131072
#define BPB   64                 // blocks per batch (reduction chunks)
#define CHUNK (N_PTS / BPB)      // 2048 elements per block
#define TPB   256
#define NACC  16                 // W, As[3], At[3], M[9]
#define NITER (CHUNK / 4 / TPB)  // 2 float4 per thread per stream

// ---------------- Kernel 1: streaming partial reduction ----------------
__global__ __launch_bounds__(TPB) void ego_partial_kernel(
    const float* __restrict__ xyz_s,    // (B,3,N)
    const float* __restrict__ wtgt,     // (B,3,N)
    const float* __restrict__ weights,  // (B,1,N)
    const float* __restrict__ label,    // (B,1,N)
    float* __restrict__ partials)       // (B, BPB, 16)
{
    const int b     = blockIdx.y;
    const int chunk = blockIdx.x;
    const int t     = threadIdx.x;

    const size_t baseN  = (size_t)b * N_PTS + (size_t)chunk * CHUNK;
    const size_t base3  = (size_t)b * 3 * N_PTS + (size_t)chunk * CHUNK;

    const float4* w4  = (const float4*)(weights + baseN);
    const float4* l4  = (const float4*)(label   + baseN);
    const float4* xs0 = (const float4*)(xyz_s + base3);
    const float4* xs1 = (const float4*)(xyz_s + base3 + N_PTS);
    const float4* xs2 = (const float4*)(xyz_s + base3 + 2 * N_PTS);
    const float4* xt0 = (const float4*)(wtgt  + base3);
    const float4* xt1 = (const float4*)(wtgt  + base3 + N_PTS);
    const float4* xt2 = (const float4*)(wtgt  + base3 + 2 * N_PTS);

    // ---- issue ALL loads first (16 float4 in flight per thread) ----
    float4 wv[NITER], lv[NITER];
    float4 a0[NITER], a1[NITER], a2[NITER];
    float4 b0[NITER], b1[NITER], b2[NITER];
#pragma unroll
    for (int k = 0; k < NITER; ++k) {
        const int i = t + k * TPB;
        wv[k] = w4[i];
        lv[k] = l4[i];
        a0[k] = xs0[i]; a1[k] = xs1[i]; a2[k] = xs2[i];
        b0[k] = xt0[i]; b1[k] = xt1[i]; b2[k] = xt2[i];
    }

    float acc[NACC];
#pragma unroll
    for (int i = 0; i < NACC; ++i) acc[i] = 0.0f;

#pragma unroll
    for (int k = 0; k < NITER; ++k) {
#define ACCUM(C)                                              \
        {                                                     \
            const float w  = wv[k].C * fabsf(lv[k].C - 1.0f); \
            const float s0 = a0[k].C, s1 = a1[k].C, s2 = a2[k].C; \
            const float t0 = b0[k].C, t1 = b1[k].C, t2 = b2[k].C; \
            acc[0] += w;                                      \
            const float ws0 = w * s0, ws1 = w * s1, ws2 = w * s2; \
            acc[1] += ws0;  acc[2] += ws1;  acc[3] += ws2;    \
            acc[4] += w * t0; acc[5] += w * t1; acc[6] += w * t2; \
            acc[7]  += ws0 * t0; acc[8]  += ws0 * t1; acc[9]  += ws0 * t2; \
            acc[10] += ws1 * t0; acc[11] += ws1 * t1; acc[12] += ws1 * t2; \
            acc[13] += ws2 * t0; acc[14] += ws2 * t1; acc[15] += ws2 * t2; \
        }
        ACCUM(x) ACCUM(y) ACCUM(z) ACCUM(w)
#undef ACCUM
    }

    // wave-level reduce (64 lanes)
#pragma unroll
    for (int i = 0; i < NACC; ++i) {
        float v = acc[i];
#pragma unroll
        for (int off = 32; off > 0; off >>= 1)
            v += __shfl_down(v, off, 64);
        acc[i] = v;
    }

    __shared__ float red[TPB / 64][NACC];
    const int wave = t >> 6;
    const int lane = t & 63;
    if (lane == 0) {
#pragma unroll
        for (int i = 0; i < NACC; ++i) red[wave][i] = acc[i];
    }
    __syncthreads();

    if (t < NACC) {
        float v = 0.0f;
#pragma unroll
        for (int wv_ = 0; wv_ < TPB / 64; ++wv_) v += red[wv_][t];
        partials[((size_t)b * BPB + chunk) * NACC + t] = v;
    }
}

// ---------------- Kernel 2: final reduce + 3x3 SVD Kabsch ----------------
__global__ __launch_bounds__(64) void ego_finalize_kernel(
    const float* __restrict__ partials,  // (B, BPB, 16)
    float* __restrict__ out,             // rot (B,3,3) then translation (B,3,1)
    int B)
{
    const int b = blockIdx.x;
    const int t = threadIdx.x;   // 0..63 == BPB

    double acc[NACC];
    const float* p = partials + ((size_t)b * BPB + t) * NACC;
#pragma unroll
    for (int i = 0; i < NACC; ++i) acc[i] = (double)p[i];

#pragma unroll
    for (int i = 0; i < NACC; ++i) {
        double v = acc[i];
#pragma unroll
        for (int off = 32; off > 0; off >>= 1)
            v += __shfl_down(v, off, 64);
        acc[i] = v;
    }

    if (t != 0) return;

    const double W     = acc[0];
    const double denom = W + 1e-6;
    double cs[3], ct[3];
#pragma unroll
    for (int d = 0; d < 3; ++d) {
        cs[d] = acc[1 + d] / denom;
        ct[d] = acc[4 + d] / denom;
    }
    const double Wn = W / denom;

    double cov[3][3];
#pragma unroll
    for (int d = 0; d < 3; ++d)
#pragma unroll
        for (int e = 0; e < 3; ++e)
            cov[d][e] = acc[7 + d * 3 + e] / denom - cs[d] * ct[e] * (2.0 - Wn);

    // --- B = cov^T cov, Jacobi eigen-decomposition -> V, lambda ---
    double Bm[3][3];
    for (int i = 0; i < 3; ++i)
        for (int j = 0; j < 3; ++j) {
            double s = 0.0;
            for (int k = 0; k < 3; ++k) s += cov[k][i] * cov[k][j];
            Bm[i][j] = s;
        }
    double V[3][3] = {{1,0,0},{0,1,0},{0,0,1}};

    // 8 fixed sweeps: quadratic convergence, far beyond fp32 needs
    for (int sweep = 0; sweep < 8; ++sweep) {
        const int pq[3][2] = {{0,1},{0,2},{1,2}};
        for (int r = 0; r < 3; ++r) {
            const int pp = pq[r][0], qq = pq[r][1];
            const double apq = Bm[pp][qq];
            if (fabs(apq) < 1e-300) continue;
            const double tau = (Bm[qq][qq] - Bm[pp][pp]) / (2.0 * apq);
            const double tt  = (tau >= 0.0 ? 1.0 : -1.0) /
                               (fabs(tau) + sqrt(1.0 + tau * tau));
            const double c = 1.0 / sqrt(1.0 + tt * tt);
            const double s = tt * c;
            for (int k = 0; k < 3; ++k) {
                const double bkp = Bm[k][pp], bkq = Bm[k][qq];
                Bm[k][pp] = c * bkp - s * bkq;
                Bm[k][qq] = s * bkp + c * bkq;
            }
            for (int k = 0; k < 3; ++k) {
                const double bpk = Bm[pp][k], bqk = Bm[qq][k];
                Bm[pp][k] = c * bpk - s * bqk;
                Bm[qq][k] = s * bpk + c * bqk;
            }
            for (int k = 0; k < 3; ++k) {
                const double vkp = V[k][pp], vkq = V[k][qq];
                V[k][pp] = c * vkp - s * vkq;
                V[k][qq] = s * vkp + c * vkq;
            }
        }
    }

    // sort eigenvalues descending, permute V columns
    double lam[3] = {Bm[0][0], Bm[1][1], Bm[2][2]};
    int idx[3] = {0, 1, 2};
    for (int i = 0; i < 2; ++i)
        for (int j = i + 1; j < 3; ++j)
            if (lam[idx[j]] > lam[idx[i]]) { int tmp = idx[i]; idx[i] = idx[j]; idx[j] = tmp; }
    double Vs[3][3];
    for (int c = 0; c < 3; ++c)
        for (int rr = 0; rr < 3; ++rr) Vs[rr][c] = V[rr][idx[c]];

    // U columns: u_c = cov * v_c / |cov*v_c| (cross-product fallback)
    double U[3][3];
    for (int c = 0; c < 3; ++c) {
        double u0 = 0, u1 = 0, u2 = 0;
        for (int k = 0; k < 3; ++k) {
            u0 += cov[0][k] * Vs[k][c];
            u1 += cov[1][k] * Vs[k][c];
            u2 += cov[2][k] * Vs[k][c];
        }
        const double nn = sqrt(u0 * u0 + u1 * u1 + u2 * u2);
        if (nn > 1e-150) {
            U[0][c] = u0 / nn; U[1][c] = u1 / nn; U[2][c] = u2 / nn;
        } else if (c == 2) {
            U[0][2] = U[1][0] * U[2][1] - U[2][0] * U[1][1];
            U[1][2] = U[2][0] * U[0][1] - U[0][0] * U[2][1];
            U[2][2] = U[0][0] * U[1][1] - U[1][0] * U[0][1];
        } else {
            U[0][c] = (c == 0); U[1][c] = (c == 1); U[2][c] = 0.0;
        }
    }

    // rot_pos = Vs * U^T
    double rot[3][3];
    for (int d = 0; d < 3; ++d)
        for (int e = 0; e < 3; ++e)
            rot[d][e] = Vs[d][0] * U[e][0] + Vs[d][1] * U[e][1] + Vs[d][2] * U[e][2];

    const double det =
        rot[0][0] * (rot[1][1] * rot[2][2] - rot[1][2] * rot[2][1]) -
        rot[0][1] * (rot[1][0] * rot[2][2] - rot[1][2] * rot[2][0]) +
        rot[0][2] * (rot[1][0] * rot[2][1] - rot[1][1] * rot[2][0]);

    if (!(det > 0.0)) {
        for (int d = 0; d < 3; ++d)
            for (int e = 0; e < 3; ++e)
                rot[d][e] = Vs[d][0] * U[e][0] + Vs[d][1] * U[e][1] - Vs[d][2] * U[e][2];
    }

    double tr[3];
    for (int d = 0; d < 3; ++d)
        tr[d] = -(rot[d][0] * cs[0] + rot[d][1] * cs[1] + rot[d][2] * cs[2]) + ct[d];

    for (int d = 0; d < 3; ++d)
        for (int e = 0; e < 3; ++e)
            out[(size_t)b * 9 + d * 3 + e] = (float)rot[d][e];
    for (int d = 0; d < 3; ++d)
        out[(size_t)B * 9 + (size_t)b * 3 + d] = (float)tr[d];
}

extern "C" void kernel_launch(void* const* d_in, const int* in_sizes, int n_in,
                              void* d_out, int out_size, void* d_ws, size_t ws_size,
                              hipStream_t stream) {
    const float* xyz_s   = (const float*)d_in[0];
    const float* wtgt    = (const float*)d_in[1];
    const float* weights = (const float*)d_in[2];
    const float* label   = (const float*)d_in[3];
    float* out = (float*)d_out;
    float* partials = (float*)d_ws;   // B*BPB*16 floats = 128 KB

    const int B = in_sizes[2] / N_PTS;   // weights has B*N elements

    dim3 grid1(BPB, B);
    ego_partial_kernel<<<grid1, TPB, 0, stream>>>(xyz_s, wtgt, weights, label, partials);
    ego_finalize_kernel<<<B, 64, 0, stream>>>(partials, out, B);
}